// Round 2
// baseline (124.243 us; speedup 1.0000x reference)
//
#include <hip/hip_runtime.h>

// SymmetricContraction via symmetrized-basis contraction.
//
// out[n,m,0]   = w0[e,m]*Sum_a S0[a] f_a   + Sum_s w2[e,s,m]*B2_s + Sum_s w4[e,s,m]*B4_s
// out[n,m,1+d] = w1[e,m]*Sum_a S1[a,d] f_a + Sum_s w3[e,s,m]*B3_sd + Sum_s w5[e,s,m]*B5_sd
// where B*_s = Sum_{monomial k} S*[k,s(,d)] * M_k(f), f = feats[n,m,0:9],
// monomials: 45 quads (a<=b), 165 cubics (a<=b<=c), S* = permutation-symmetrized bases.
//
// S table is species/mul independent: 2568 floats = 10.3 KB -> d_ws (tiny, no
// OOB risk; R1's 4.5 MB ws table corrupted adjacent allocations).
//
// Output row layout (512 floats): [0..127]=d0 per m ; [128+3m+d] = vector part.

#define N_NODES 2048
#define MUL     128
#define NROW    1152
#define NQ      45
#define NC      165
// float4-unit layout of S: [0,9) linear recs (pad to 12), [12,147) quad recs
// (45 x 3), [147,642) cubic recs (165 x 3).
#define Q4_BASE 12
#define C4_BASE 147
#define S4_TOTAL 642   // float4s -> 10272 bytes

// ---------------------------------------------------------------------------
// Kernel 1: build symmetrized basis table S into d_ws. One block, 256 threads.
// ---------------------------------------------------------------------------
__global__ void k_prep(const float* __restrict__ b0, const float* __restrict__ b1,
                       const float* __restrict__ b2, const float* __restrict__ b3,
                       const float* __restrict__ b4, const float* __restrict__ b5,
                       float4* __restrict__ S) {
    const int t = threadIdx.x;
    if (t < 9) {
        // linear record a: [S0[a], S1[a][0..2]]
        S[t] = make_float4(b0[t], b1[t * 3 + 0], b1[t * 3 + 1], b1[t * 3 + 2]);
    } else if (t < Q4_BASE) {
        S[t] = make_float4(0.f, 0.f, 0.f, 0.f);   // pad
    } else if (t < Q4_BASE + NQ) {
        const int k = t - Q4_BASE;
        // decode k -> (a<=b), lexicographic
        int a = -1, b = -1, kk = k;
        for (int aa = 0; aa < 9 && a < 0; ++aa) {
            const int cnt = 9 - aa;
            if (kk < cnt) { a = aa; b = aa + kk; } else kk -= cnt;
        }
        const float mult = (a == b) ? 0.5f : 1.0f;
        const int i1 = a * 9 + b, i2 = b * 9 + a;
        float s2[3], s3[6];
        for (int s = 0; s < 3; ++s)
            s2[s] = (b2[i1 * 3 + s] + b2[i2 * 3 + s]) * mult;
        for (int s = 0; s < 2; ++s)
            for (int d = 0; d < 3; ++d)
                s3[s * 3 + d] = (b3[(i1 * 2 + s) * 3 + d] + b3[(i2 * 2 + s) * 3 + d]) * mult;
        S[Q4_BASE + k * 3 + 0] = make_float4(s2[0], s2[1], s2[2], 0.f);
        S[Q4_BASE + k * 3 + 1] = make_float4(s3[0], s3[1], s3[2], s3[3]);
        S[Q4_BASE + k * 3 + 2] = make_float4(s3[4], s3[5], 0.f, 0.f);
    } else if (t < Q4_BASE + NQ + NC) {
        const int k = t - Q4_BASE - NQ;
        // decode k -> (a<=b<=c), lexicographic
        int a = -1, b = -1, c = -1, kk = k;
        for (int aa = 0; aa < 9 && a < 0; ++aa)
            for (int bb = aa; bb < 9 && a < 0; ++bb) {
                const int cnt = 9 - bb;
                if (kk < cnt) { a = aa; b = bb; c = bb + kk; } else kk -= cnt;
            }
        const float mult = (a == b && b == c) ? (1.0f / 6.0f)
                         : ((a == b || b == c) ? 0.5f : 1.0f);
        int p[6];
        p[0] = (a * 9 + b) * 9 + c;  p[1] = (a * 9 + c) * 9 + b;
        p[2] = (b * 9 + a) * 9 + c;  p[3] = (b * 9 + c) * 9 + a;
        p[4] = (c * 9 + a) * 9 + b;  p[5] = (c * 9 + b) * 9 + a;
        float s4[4], s5[6];
        for (int s = 0; s < 4; ++s) {
            float v = 0.f;
            for (int j = 0; j < 6; ++j) v += b4[p[j] * 4 + s];
            s4[s] = v * mult;
        }
        for (int s = 0; s < 2; ++s)
            for (int d = 0; d < 3; ++d) {
                float v = 0.f;
                for (int j = 0; j < 6; ++j) v += b5[(p[j] * 2 + s) * 3 + d];
                s5[s * 3 + d] = v * mult;
            }
        S[C4_BASE + k * 3 + 0] = make_float4(s4[0], s4[1], s4[2], s4[3]);
        S[C4_BASE + k * 3 + 1] = make_float4(s5[0], s5[1], s5[2], s5[3]);
        S[C4_BASE + k * 3 + 2] = make_float4(s5[4], s5[5], 0.f, 0.f);
    }
}

// ---------------------------------------------------------------------------
// Kernel 2: evaluate. Block = 256 threads; lane m = tid&127, node pair
// nbase = blockIdx*4 + (tid>>7)*2; each thread does 2 nodes (amortizes LDS).
// ---------------------------------------------------------------------------
__global__ __launch_bounds__(256) void k_eval(
        const float* __restrict__ nf, const int* __restrict__ species,
        const float* __restrict__ w0, const float* __restrict__ w1,
        const float* __restrict__ w2, const float* __restrict__ w3,
        const float* __restrict__ w4, const float* __restrict__ w5,
        const float4* __restrict__ Sg, float* __restrict__ out) {
    __shared__ float4 S[S4_TOTAL];
    const int tid = threadIdx.x;
    for (int i = tid; i < S4_TOTAL; i += 256) S[i] = Sg[i];
    __syncthreads();

    const int m = tid & 127;
    const int nbase = blockIdx.x * 4 + (tid >> 7) * 2;

    float f[2][9];
    float wv0[2], wv1[2], wv2[2][3], wv3[2][2], wv4[2][4], wv5[2][2];
#pragma unroll
    for (int i = 0; i < 2; ++i) {
        const int n = nbase + i;
        const float* __restrict__ row = nf + (size_t)n * NROW;
        f[i][0] = row[m];
#pragma unroll
        for (int j = 0; j < 3; ++j) f[i][1 + j] = row[128 + 3 * m + j];
#pragma unroll
        for (int j = 0; j < 5; ++j) f[i][4 + j] = row[512 + 5 * m + j];
        const int e = species[n];
        wv0[i] = w0[e * MUL + m];
        wv1[i] = w1[e * MUL + m];
#pragma unroll
        for (int s = 0; s < 3; ++s) wv2[i][s] = w2[(e * 3 + s) * MUL + m];
#pragma unroll
        for (int s = 0; s < 2; ++s) wv3[i][s] = w3[(e * 2 + s) * MUL + m];
#pragma unroll
        for (int s = 0; s < 4; ++s) wv4[i][s] = w4[(e * 4 + s) * MUL + m];
#pragma unroll
        for (int s = 0; s < 2; ++s) wv5[i][s] = w5[(e * 2 + s) * MUL + m];
    }

    float A0[2] = {0.f, 0.f};
    float A1[2][3] = {};
    float B2[2][3] = {}, B3[2][6] = {};
    float B4[2][4] = {}, B5[2][6] = {};

    // linear
#pragma unroll
    for (int a = 0; a < 9; ++a) {
        const float4 L = S[a];
#pragma unroll
        for (int i = 0; i < 2; ++i) {
            A0[i]    += L.x * f[i][a];
            A1[i][0] += L.y * f[i][a];
            A1[i][1] += L.z * f[i][a];
            A1[i][2] += L.w * f[i][a];
        }
    }

    // quad + cubic, record order matches k_prep's lexicographic decode
    int kq = 0, kc = 0;
#pragma unroll
    for (int a = 0; a < 9; ++a) {
#pragma unroll
        for (int b = a; b < 9; ++b) {
            float q[2];
            q[0] = f[0][a] * f[0][b];
            q[1] = f[1][a] * f[1][b];
            {
                const float4 r0 = S[Q4_BASE + kq * 3 + 0];
                const float4 r1 = S[Q4_BASE + kq * 3 + 1];
                const float4 r2 = S[Q4_BASE + kq * 3 + 2];
#pragma unroll
                for (int i = 0; i < 2; ++i) {
                    B2[i][0] += q[i] * r0.x; B2[i][1] += q[i] * r0.y; B2[i][2] += q[i] * r0.z;
                    B3[i][0] += q[i] * r1.x; B3[i][1] += q[i] * r1.y; B3[i][2] += q[i] * r1.z;
                    B3[i][3] += q[i] * r1.w; B3[i][4] += q[i] * r2.x; B3[i][5] += q[i] * r2.y;
                }
                ++kq;
            }
#pragma unroll
            for (int c = b; c < 9; ++c) {
                const float4 r0 = S[C4_BASE + kc * 3 + 0];
                const float4 r1 = S[C4_BASE + kc * 3 + 1];
                const float4 r2 = S[C4_BASE + kc * 3 + 2];
#pragma unroll
                for (int i = 0; i < 2; ++i) {
                    const float tt = q[i] * f[i][c];
                    B4[i][0] += tt * r0.x; B4[i][1] += tt * r0.y;
                    B4[i][2] += tt * r0.z; B4[i][3] += tt * r0.w;
                    B5[i][0] += tt * r1.x; B5[i][1] += tt * r1.y; B5[i][2] += tt * r1.z;
                    B5[i][3] += tt * r1.w; B5[i][4] += tt * r2.x; B5[i][5] += tt * r2.y;
                }
                ++kc;
            }
        }
    }

    // epilogue: apply per-(e,m) weights, write
#pragma unroll
    for (int i = 0; i < 2; ++i) {
        const int n = nbase + i;
        float* __restrict__ orow = out + (size_t)n * 512;
        float o0 = wv0[i] * A0[i]
                 + wv2[i][0] * B2[i][0] + wv2[i][1] * B2[i][1] + wv2[i][2] * B2[i][2]
                 + wv4[i][0] * B4[i][0] + wv4[i][1] * B4[i][1]
                 + wv4[i][2] * B4[i][2] + wv4[i][3] * B4[i][3];
        orow[m] = o0;
#pragma unroll
        for (int d = 0; d < 3; ++d) {
            float od = wv1[i] * A1[i][d]
                     + wv3[i][0] * B3[i][d]     + wv3[i][1] * B3[i][3 + d]
                     + wv5[i][0] * B5[i][d]     + wv5[i][1] * B5[i][3 + d];
            orow[128 + 3 * m + d] = od;
        }
    }
}

// ---------------------------------------------------------------------------
extern "C" void kernel_launch(void* const* d_in, const int* in_sizes, int n_in,
                              void* d_out, int out_size, void* d_ws, size_t ws_size,
                              hipStream_t stream) {
    const float* nf      = (const float*)d_in[0];
    const int*   species = (const int*)d_in[1];
    const float* b0 = (const float*)d_in[2];  const float* w0 = (const float*)d_in[3];
    const float* b1 = (const float*)d_in[4];  const float* w1 = (const float*)d_in[5];
    const float* b2 = (const float*)d_in[6];  const float* w2 = (const float*)d_in[7];
    const float* b3 = (const float*)d_in[8];  const float* w3 = (const float*)d_in[9];
    const float* b4 = (const float*)d_in[10]; const float* w4 = (const float*)d_in[11];
    const float* b5 = (const float*)d_in[12]; const float* w5 = (const float*)d_in[13];
    float* out = (float*)d_out;

    float4* S = (float4*)d_ws;   // 642 float4 = 10,272 bytes only

    hipLaunchKernelGGL(k_prep, dim3(1), dim3(256), 0, stream,
                       b0, b1, b2, b3, b4, b5, S);
    // 512 blocks x 256 threads; each thread: 2 nodes x 1 mul
    hipLaunchKernelGGL(k_eval, dim3(512), dim3(256), 0, stream,
                       nf, species, w0, w1, w2, w3, w4, w5,
                       (const float4*)S, out);
}

// Round 4
// 114.039 us; speedup vs baseline: 1.0895x; 1.0895x over previous
//
#include <hip/hip_runtime.h>

// SymmetricContraction via symmetrized-basis contraction.
//
// out[n,m,0]   = w0[e,m]*Sum_a S0[a] f_a   + Sum_s w2[e,s,m]*B2_s + Sum_s w4[e,s,m]*B4_s
// out[n,m,1+d] = w1[e,m]*Sum_a S1[a,d] f_a + Sum_s w3[e,s,m]*B3_sd + Sum_s w5[e,s,m]*B5_sd
// where B*_s = Sum_{monomial k} S*[k,s(,d)] * M_k(f), f = feats[n,m,0:9],
// monomials: 45 quads (a<=b), 165 cubics (a<=b<=c), S* = permutation-symmetrized bases.
//
// R3 -> R4: same scalar-path plan as R3, but compile-clean:
//  - float4 (HIP class type) can't be loaded through address_space(4) refs;
//    use clang's native ext_vector_type(4) float instead (builtin vector, no ctors).
//  - hipcc type-checks kernel bodies in the HOST pass too -> AS(4) code is
//    guarded by __HIP_DEVICE_COMPILE__ (host pass sees an empty body stub).
// S is wave-uniform at compile-time offsets -> constant-AS loads become
// s_load_dwordx4/x8/x16 into SGPRs; FMAs consume the SGPR operand directly.
//
// Output row layout (512 floats): [0..127]=d0 per m ; [128+3m+d] = vector part.

#define N_NODES 2048
#define MUL     128
#define NROW    1152
#define NQ      45
#define NC      165
// float4-unit layout of S: [0,9) linear recs (pad to 12), [12,147) quad recs
// (45 x 3), [147,642) cubic recs (165 x 3).
#define Q4_BASE 12
#define C4_BASE 147
#define S4_TOTAL 642   // float4s -> 10272 bytes (d_ws usage; ws is much larger)

// ---------------------------------------------------------------------------
// Kernel 1: build symmetrized basis table S into d_ws. One block, 256 threads.
// ---------------------------------------------------------------------------
__global__ void k_prep(const float* __restrict__ b0, const float* __restrict__ b1,
                       const float* __restrict__ b2, const float* __restrict__ b3,
                       const float* __restrict__ b4, const float* __restrict__ b5,
                       float4* __restrict__ S) {
    const int t = threadIdx.x;
    if (t < 9) {
        // linear record a: [S0[a], S1[a][0..2]]
        S[t] = make_float4(b0[t], b1[t * 3 + 0], b1[t * 3 + 1], b1[t * 3 + 2]);
    } else if (t < Q4_BASE) {
        S[t] = make_float4(0.f, 0.f, 0.f, 0.f);   // pad
    } else if (t < Q4_BASE + NQ) {
        const int k = t - Q4_BASE;
        // decode k -> (a<=b), lexicographic
        int a = -1, b = -1, kk = k;
        for (int aa = 0; aa < 9 && a < 0; ++aa) {
            const int cnt = 9 - aa;
            if (kk < cnt) { a = aa; b = aa + kk; } else kk -= cnt;
        }
        const float mult = (a == b) ? 0.5f : 1.0f;
        const int i1 = a * 9 + b, i2 = b * 9 + a;
        float s2[3], s3[6];
        for (int s = 0; s < 3; ++s)
            s2[s] = (b2[i1 * 3 + s] + b2[i2 * 3 + s]) * mult;
        for (int s = 0; s < 2; ++s)
            for (int d = 0; d < 3; ++d)
                s3[s * 3 + d] = (b3[(i1 * 2 + s) * 3 + d] + b3[(i2 * 2 + s) * 3 + d]) * mult;
        S[Q4_BASE + k * 3 + 0] = make_float4(s2[0], s2[1], s2[2], 0.f);
        S[Q4_BASE + k * 3 + 1] = make_float4(s3[0], s3[1], s3[2], s3[3]);
        S[Q4_BASE + k * 3 + 2] = make_float4(s3[4], s3[5], 0.f, 0.f);
    } else if (t < Q4_BASE + NQ + NC) {
        const int k = t - Q4_BASE - NQ;
        // decode k -> (a<=b<=c), lexicographic
        int a = -1, b = -1, c = -1, kk = k;
        for (int aa = 0; aa < 9 && a < 0; ++aa)
            for (int bb = aa; bb < 9 && a < 0; ++bb) {
                const int cnt = 9 - bb;
                if (kk < cnt) { a = aa; b = bb; c = bb + kk; } else kk -= cnt;
            }
        const float mult = (a == b && b == c) ? (1.0f / 6.0f)
                         : ((a == b || b == c) ? 0.5f : 1.0f);
        int p[6];
        p[0] = (a * 9 + b) * 9 + c;  p[1] = (a * 9 + c) * 9 + b;
        p[2] = (b * 9 + a) * 9 + c;  p[3] = (b * 9 + c) * 9 + a;
        p[4] = (c * 9 + a) * 9 + b;  p[5] = (c * 9 + b) * 9 + a;
        float s4[4], s5[6];
        for (int s = 0; s < 4; ++s) {
            float v = 0.f;
            for (int j = 0; j < 6; ++j) v += b4[p[j] * 4 + s];
            s4[s] = v * mult;
        }
        for (int s = 0; s < 2; ++s)
            for (int d = 0; d < 3; ++d) {
                float v = 0.f;
                for (int j = 0; j < 6; ++j) v += b5[(p[j] * 2 + s) * 3 + d];
                s5[s * 3 + d] = v * mult;
            }
        S[C4_BASE + k * 3 + 0] = make_float4(s4[0], s4[1], s4[2], s4[3]);
        S[C4_BASE + k * 3 + 1] = make_float4(s5[0], s5[1], s5[2], s5[3]);
        S[C4_BASE + k * 3 + 2] = make_float4(s5[4], s5[5], 0.f, 0.f);
    }
}

// ---------------------------------------------------------------------------
// Kernel 2: evaluate. 1 node per thread. Block = 256: lane m = tid&127,
// node n = blockIdx*2 + (tid>>7). Within each wave n (hence species e) is
// uniform and m spans 64 consecutive values -> all weight loads coalesced.
// S reads go through address_space(4) -> s_load (scalar cache, SGPR results).
// ---------------------------------------------------------------------------
typedef float fvec4 __attribute__((ext_vector_type(4)));

__global__ __launch_bounds__(256) void k_eval(
        const float* __restrict__ nf, const int* __restrict__ species,
        const float* __restrict__ w0, const float* __restrict__ w1,
        const float* __restrict__ w2, const float* __restrict__ w3,
        const float* __restrict__ w4, const float* __restrict__ w5,
        const float* __restrict__ Sg, float* __restrict__ out) {
#if defined(__HIP_DEVICE_COMPILE__)
    typedef const __attribute__((address_space(4))) fvec4* S4cp;
    S4cp S = (S4cp)(unsigned long long)Sg;   // reinterpret into constant AS

    const int tid = threadIdx.x;
    const int m = tid & 127;
    const int n = blockIdx.x * 2 + (tid >> 7);

    const float* __restrict__ row = nf + (size_t)n * NROW;
    float f[9];
    f[0] = row[m];
#pragma unroll
    for (int j = 0; j < 3; ++j) f[1 + j] = row[128 + 3 * m + j];
#pragma unroll
    for (int j = 0; j < 5; ++j) f[4 + j] = row[512 + 5 * m + j];

    const int e = species[n];
    const float wv0 = w0[e * MUL + m];
    const float wv1 = w1[e * MUL + m];
    float wv2[3], wv3[2], wv4[4], wv5[2];
#pragma unroll
    for (int s = 0; s < 3; ++s) wv2[s] = w2[(e * 3 + s) * MUL + m];
#pragma unroll
    for (int s = 0; s < 2; ++s) wv3[s] = w3[(e * 2 + s) * MUL + m];
#pragma unroll
    for (int s = 0; s < 4; ++s) wv4[s] = w4[(e * 4 + s) * MUL + m];
#pragma unroll
    for (int s = 0; s < 2; ++s) wv5[s] = w5[(e * 2 + s) * MUL + m];

    float A0 = 0.f;
    float A1[3] = {};
    float B2[3] = {}, B3[6] = {};
    float B4[4] = {}, B5[6] = {};

    // linear
#pragma unroll
    for (int a = 0; a < 9; ++a) {
        const fvec4 L = S[a];
        A0    += L.x * f[a];
        A1[0] += L.y * f[a];
        A1[1] += L.z * f[a];
        A1[2] += L.w * f[a];
    }

    // quad + cubic, record order matches k_prep's lexicographic decode
    int kq = 0, kc = 0;
#pragma unroll
    for (int a = 0; a < 9; ++a) {
#pragma unroll
        for (int b = a; b < 9; ++b) {
            const float q = f[a] * f[b];
            {
                const fvec4 r0 = S[Q4_BASE + kq * 3 + 0];
                const fvec4 r1 = S[Q4_BASE + kq * 3 + 1];
                const fvec4 r2 = S[Q4_BASE + kq * 3 + 2];
                B2[0] += q * r0.x; B2[1] += q * r0.y; B2[2] += q * r0.z;
                B3[0] += q * r1.x; B3[1] += q * r1.y; B3[2] += q * r1.z;
                B3[3] += q * r1.w; B3[4] += q * r2.x; B3[5] += q * r2.y;
                ++kq;
            }
#pragma unroll
            for (int c = b; c < 9; ++c) {
                const fvec4 r0 = S[C4_BASE + kc * 3 + 0];
                const fvec4 r1 = S[C4_BASE + kc * 3 + 1];
                const fvec4 r2 = S[C4_BASE + kc * 3 + 2];
                const float tt = q * f[c];
                B4[0] += tt * r0.x; B4[1] += tt * r0.y;
                B4[2] += tt * r0.z; B4[3] += tt * r0.w;
                B5[0] += tt * r1.x; B5[1] += tt * r1.y; B5[2] += tt * r1.z;
                B5[3] += tt * r1.w; B5[4] += tt * r2.x; B5[5] += tt * r2.y;
                ++kc;
            }
        }
    }

    // epilogue: apply per-(e,m) weights, write
    float* __restrict__ orow = out + (size_t)n * 512;
    orow[m] = wv0 * A0
            + wv2[0] * B2[0] + wv2[1] * B2[1] + wv2[2] * B2[2]
            + wv4[0] * B4[0] + wv4[1] * B4[1] + wv4[2] * B4[2] + wv4[3] * B4[3];
#pragma unroll
    for (int d = 0; d < 3; ++d) {
        orow[128 + 3 * m + d] = wv1 * A1[d]
                              + wv3[0] * B3[d] + wv3[1] * B3[3 + d]
                              + wv5[0] * B5[d] + wv5[1] * B5[3 + d];
    }
#endif  // __HIP_DEVICE_COMPILE__
}

// ---------------------------------------------------------------------------
extern "C" void kernel_launch(void* const* d_in, const int* in_sizes, int n_in,
                              void* d_out, int out_size, void* d_ws, size_t ws_size,
                              hipStream_t stream) {
    const float* nf      = (const float*)d_in[0];
    const int*   species = (const int*)d_in[1];
    const float* b0 = (const float*)d_in[2];  const float* w0 = (const float*)d_in[3];
    const float* b1 = (const float*)d_in[4];  const float* w1 = (const float*)d_in[5];
    const float* b2 = (const float*)d_in[6];  const float* w2 = (const float*)d_in[7];
    const float* b3 = (const float*)d_in[8];  const float* w3 = (const float*)d_in[9];
    const float* b4 = (const float*)d_in[10]; const float* w4 = (const float*)d_in[11];
    const float* b5 = (const float*)d_in[12]; const float* w5 = (const float*)d_in[13];
    float* out = (float*)d_out;

    float4* S = (float4*)d_ws;   // 642 float4 = 10,272 bytes only

    hipLaunchKernelGGL(k_prep, dim3(1), dim3(256), 0, stream,
                       b0, b1, b2, b3, b4, b5, S);
    // 1024 blocks x 256 threads; each thread: 1 node x 1 mul
    hipLaunchKernelGGL(k_eval, dim3(1024), dim3(256), 0, stream,
                       nf, species, w0, w1, w2, w3, w4, w5,
                       (const float*)S, out);
}

// Round 5
// 109.561 us; speedup vs baseline: 1.1340x; 1.0409x over previous
//
#include <hip/hip_runtime.h>

// SymmetricContraction via symmetrized-basis contraction.
//
// out[n,m,0]   = w0[e,m]*Sum_a S0[a] f_a   + Sum_s w2[e,s,m]*B2_s + Sum_s w4[e,s,m]*B4_s
// out[n,m,1+d] = w1[e,m]*Sum_a S1[a,d] f_a + Sum_s w3[e,s,m]*B3_sd + Sum_s w5[e,s,m]*B5_sd
// where B*_s = Sum_{monomial k} S*[k,s(,d)] * M_k(f), f = feats[n,m,0:9],
// monomials: 45 quads (a<=b), 165 cubics (a<=b<=c), S* = permutation-symmetrized bases.
//
// R4 -> R5: k_eval was latency-bound (s_load chains, only 4 waves/SIMD possible
// at 1 thread per (n,m)). Split-K: each (n,m) is handled by TWO threads in the
// same block (wave-uniform halves): half0 = linear+quads+cubics[k<57],
// half1 = cubics[k>=57]. Half1's 10 partial accumulators go through LDS; half0
// reduces + applies weights. Grid 2048 blocks (1 node/block), 8 blocks/CU,
// __launch_bounds__(256,8) -> 32 waves/CU: 2x latency hiding, half-length
// per-wave s_load streams.
//
// Output row layout (512 floats): [0..127]=d0 per m ; [128+3m+d] = vector part.

#define N_NODES 2048
#define MUL     128
#define NROW    1152
#define NQ      45
#define NC      165
#define KSPLIT  57      // cubic split point between half0 / half1
// float4-unit layout of S: [0,9) linear recs (pad to 12), [12,147) quad recs
// (45 x 3), [147,642) cubic recs (165 x 3).
#define Q4_BASE 12
#define C4_BASE 147
#define S4_TOTAL 642   // float4s -> 10272 bytes (d_ws usage)

// ---------------------------------------------------------------------------
// Kernel 1: build symmetrized basis table S into d_ws. One block, 256 threads.
// ---------------------------------------------------------------------------
__global__ void k_prep(const float* __restrict__ b0, const float* __restrict__ b1,
                       const float* __restrict__ b2, const float* __restrict__ b3,
                       const float* __restrict__ b4, const float* __restrict__ b5,
                       float4* __restrict__ S) {
    const int t = threadIdx.x;
    if (t < 9) {
        S[t] = make_float4(b0[t], b1[t * 3 + 0], b1[t * 3 + 1], b1[t * 3 + 2]);
    } else if (t < Q4_BASE) {
        S[t] = make_float4(0.f, 0.f, 0.f, 0.f);   // pad
    } else if (t < Q4_BASE + NQ) {
        const int k = t - Q4_BASE;
        int a = -1, b = -1, kk = k;
        for (int aa = 0; aa < 9 && a < 0; ++aa) {
            const int cnt = 9 - aa;
            if (kk < cnt) { a = aa; b = aa + kk; } else kk -= cnt;
        }
        const float mult = (a == b) ? 0.5f : 1.0f;
        const int i1 = a * 9 + b, i2 = b * 9 + a;
        float s2[3], s3[6];
        for (int s = 0; s < 3; ++s)
            s2[s] = (b2[i1 * 3 + s] + b2[i2 * 3 + s]) * mult;
        for (int s = 0; s < 2; ++s)
            for (int d = 0; d < 3; ++d)
                s3[s * 3 + d] = (b3[(i1 * 2 + s) * 3 + d] + b3[(i2 * 2 + s) * 3 + d]) * mult;
        S[Q4_BASE + k * 3 + 0] = make_float4(s2[0], s2[1], s2[2], 0.f);
        S[Q4_BASE + k * 3 + 1] = make_float4(s3[0], s3[1], s3[2], s3[3]);
        S[Q4_BASE + k * 3 + 2] = make_float4(s3[4], s3[5], 0.f, 0.f);
    } else if (t < Q4_BASE + NQ + NC) {
        const int k = t - Q4_BASE - NQ;
        int a = -1, b = -1, c = -1, kk = k;
        for (int aa = 0; aa < 9 && a < 0; ++aa)
            for (int bb = aa; bb < 9 && a < 0; ++bb) {
                const int cnt = 9 - bb;
                if (kk < cnt) { a = aa; b = bb; c = bb + kk; } else kk -= cnt;
            }
        const float mult = (a == b && b == c) ? (1.0f / 6.0f)
                         : ((a == b || b == c) ? 0.5f : 1.0f);
        int p[6];
        p[0] = (a * 9 + b) * 9 + c;  p[1] = (a * 9 + c) * 9 + b;
        p[2] = (b * 9 + a) * 9 + c;  p[3] = (b * 9 + c) * 9 + a;
        p[4] = (c * 9 + a) * 9 + b;  p[5] = (c * 9 + b) * 9 + a;
        float s4[4], s5[6];
        for (int s = 0; s < 4; ++s) {
            float v = 0.f;
            for (int j = 0; j < 6; ++j) v += b4[p[j] * 4 + s];
            s4[s] = v * mult;
        }
        for (int s = 0; s < 2; ++s)
            for (int d = 0; d < 3; ++d) {
                float v = 0.f;
                for (int j = 0; j < 6; ++j) v += b5[(p[j] * 2 + s) * 3 + d];
                s5[s * 3 + d] = v * mult;
            }
        S[C4_BASE + k * 3 + 0] = make_float4(s4[0], s4[1], s4[2], s4[3]);
        S[C4_BASE + k * 3 + 1] = make_float4(s5[0], s5[1], s5[2], s5[3]);
        S[C4_BASE + k * 3 + 2] = make_float4(s5[4], s5[5], 0.f, 0.f);
    }
}

// ---------------------------------------------------------------------------
// Kernel 2: evaluate, split-K. One node per block. tid: m = tid&127,
// half = tid>>7 (wave-uniform). S reads through address_space(4) -> s_load.
// ---------------------------------------------------------------------------
typedef float fvec4 __attribute__((ext_vector_type(4)));

__global__ __launch_bounds__(256, 8) void k_eval(
        const float* __restrict__ nf, const int* __restrict__ species,
        const float* __restrict__ w0, const float* __restrict__ w1,
        const float* __restrict__ w2, const float* __restrict__ w3,
        const float* __restrict__ w4, const float* __restrict__ w5,
        const float* __restrict__ Sg, float* __restrict__ out) {
#if defined(__HIP_DEVICE_COMPILE__)
    typedef const __attribute__((address_space(4))) fvec4* S4cp;
    S4cp S = (S4cp)(unsigned long long)Sg;   // reinterpret into constant AS

    __shared__ float red[MUL * 12];          // half1 partials: B4[4],B5[6] per m

    const int tid = threadIdx.x;
    const int m = tid & 127;
    const int half = tid >> 7;               // wave-uniform (waves 0,1 vs 2,3)
    const int n = blockIdx.x;

    const float* __restrict__ row = nf + (size_t)n * NROW;
    float f[9];
    f[0] = row[m];
#pragma unroll
    for (int j = 0; j < 3; ++j) f[1 + j] = row[128 + 3 * m + j];
#pragma unroll
    for (int j = 0; j < 5; ++j) f[4 + j] = row[512 + 5 * m + j];

    float A0 = 0.f, A1[3] = {};
    float B2[3] = {}, B3[6] = {};
    float B4[4] = {}, B5[6] = {};

    if (half == 1) {
        // ---- cubics kc >= KSPLIT ----
        int kc = 0;
#pragma unroll
        for (int a = 0; a < 9; ++a) {
#pragma unroll
            for (int b = a; b < 9; ++b) {
                const float q = f[a] * f[b];
#pragma unroll
                for (int c = b; c < 9; ++c) {
                    if (kc >= KSPLIT) {      // compile-time folded per iteration
                        const fvec4 r0 = S[C4_BASE + kc * 3 + 0];
                        const fvec4 r1 = S[C4_BASE + kc * 3 + 1];
                        const fvec4 r2 = S[C4_BASE + kc * 3 + 2];
                        const float tt = q * f[c];
                        B4[0] += tt * r0.x; B4[1] += tt * r0.y;
                        B4[2] += tt * r0.z; B4[3] += tt * r0.w;
                        B5[0] += tt * r1.x; B5[1] += tt * r1.y; B5[2] += tt * r1.z;
                        B5[3] += tt * r1.w; B5[4] += tt * r2.x; B5[5] += tt * r2.y;
                    }
                    ++kc;
                }
            }
        }
        float* __restrict__ dst = &red[m * 12];
#pragma unroll
        for (int j = 0; j < 4; ++j) dst[j] = B4[j];
#pragma unroll
        for (int j = 0; j < 6; ++j) dst[4 + j] = B5[j];
    } else {
        // ---- linear ----
#pragma unroll
        for (int a = 0; a < 9; ++a) {
            const fvec4 L = S[a];
            A0    += L.x * f[a];
            A1[0] += L.y * f[a];
            A1[1] += L.z * f[a];
            A1[2] += L.w * f[a];
        }
        // ---- quads + cubics kc < KSPLIT ----
        int kq = 0, kc = 0;
#pragma unroll
        for (int a = 0; a < 9; ++a) {
#pragma unroll
            for (int b = a; b < 9; ++b) {
                const float q = f[a] * f[b];
                {
                    const fvec4 r0 = S[Q4_BASE + kq * 3 + 0];
                    const fvec4 r1 = S[Q4_BASE + kq * 3 + 1];
                    const fvec4 r2 = S[Q4_BASE + kq * 3 + 2];
                    B2[0] += q * r0.x; B2[1] += q * r0.y; B2[2] += q * r0.z;
                    B3[0] += q * r1.x; B3[1] += q * r1.y; B3[2] += q * r1.z;
                    B3[3] += q * r1.w; B3[4] += q * r2.x; B3[5] += q * r2.y;
                    ++kq;
                }
#pragma unroll
                for (int c = b; c < 9; ++c) {
                    if (kc < KSPLIT) {       // compile-time folded per iteration
                        const fvec4 r0 = S[C4_BASE + kc * 3 + 0];
                        const fvec4 r1 = S[C4_BASE + kc * 3 + 1];
                        const fvec4 r2 = S[C4_BASE + kc * 3 + 2];
                        const float tt = q * f[c];
                        B4[0] += tt * r0.x; B4[1] += tt * r0.y;
                        B4[2] += tt * r0.z; B4[3] += tt * r0.w;
                        B5[0] += tt * r1.x; B5[1] += tt * r1.y; B5[2] += tt * r1.z;
                        B5[3] += tt * r1.w; B5[4] += tt * r2.x; B5[5] += tt * r2.y;
                    }
                    ++kc;
                }
            }
        }
    }

    __syncthreads();

    if (half == 0) {
        // reduce half1's partials
        const float* __restrict__ src = &red[m * 12];
#pragma unroll
        for (int j = 0; j < 4; ++j) B4[j] += src[j];
#pragma unroll
        for (int j = 0; j < 6; ++j) B5[j] += src[4 + j];

        const int e = species[n];
        const float wv0 = w0[e * MUL + m];
        const float wv1 = w1[e * MUL + m];
        float wv2[3], wv3[2], wv4[4], wv5[2];
#pragma unroll
        for (int s = 0; s < 3; ++s) wv2[s] = w2[(e * 3 + s) * MUL + m];
#pragma unroll
        for (int s = 0; s < 2; ++s) wv3[s] = w3[(e * 2 + s) * MUL + m];
#pragma unroll
        for (int s = 0; s < 4; ++s) wv4[s] = w4[(e * 4 + s) * MUL + m];
#pragma unroll
        for (int s = 0; s < 2; ++s) wv5[s] = w5[(e * 2 + s) * MUL + m];

        float* __restrict__ orow = out + (size_t)n * 512;
        orow[m] = wv0 * A0
                + wv2[0] * B2[0] + wv2[1] * B2[1] + wv2[2] * B2[2]
                + wv4[0] * B4[0] + wv4[1] * B4[1] + wv4[2] * B4[2] + wv4[3] * B4[3];
#pragma unroll
        for (int d = 0; d < 3; ++d) {
            orow[128 + 3 * m + d] = wv1 * A1[d]
                                  + wv3[0] * B3[d] + wv3[1] * B3[3 + d]
                                  + wv5[0] * B5[d] + wv5[1] * B5[3 + d];
        }
    }
#endif  // __HIP_DEVICE_COMPILE__
}

// ---------------------------------------------------------------------------
extern "C" void kernel_launch(void* const* d_in, const int* in_sizes, int n_in,
                              void* d_out, int out_size, void* d_ws, size_t ws_size,
                              hipStream_t stream) {
    const float* nf      = (const float*)d_in[0];
    const int*   species = (const int*)d_in[1];
    const float* b0 = (const float*)d_in[2];  const float* w0 = (const float*)d_in[3];
    const float* b1 = (const float*)d_in[4];  const float* w1 = (const float*)d_in[5];
    const float* b2 = (const float*)d_in[6];  const float* w2 = (const float*)d_in[7];
    const float* b3 = (const float*)d_in[8];  const float* w3 = (const float*)d_in[9];
    const float* b4 = (const float*)d_in[10]; const float* w4 = (const float*)d_in[11];
    const float* b5 = (const float*)d_in[12]; const float* w5 = (const float*)d_in[13];
    float* out = (float*)d_out;

    float4* S = (float4*)d_ws;   // 642 float4 = 10,272 bytes only

    hipLaunchKernelGGL(k_prep, dim3(1), dim3(256), 0, stream,
                       b0, b1, b2, b3, b4, b5, S);
    // 2048 blocks x 256 threads; block = 1 node, 128 m x 2 K-halves
    hipLaunchKernelGGL(k_eval, dim3(N_NODES), dim3(256), 0, stream,
                       nf, species, w0, w1, w2, w3, w4, w5,
                       (const float*)S, out);
}